// Round 2
// baseline (88.104 us; speedup 1.0000x reference)
//
#include <hip/hip_runtime.h>
#include <hip/hip_bf16.h>

#define NA 4
#define BB 256
#define DDm 128
#define KKm 256   // hidden = 2*D

typedef __attribute__((ext_vector_type(4))) float f32x4;
typedef __attribute__((ext_vector_type(4))) unsigned int u32x4;
typedef __attribute__((ext_vector_type(8))) short bf16x8;

// RNE float -> bf16 bits
__device__ __forceinline__ unsigned int f2bf(float f) {
  unsigned int bits = __builtin_bit_cast(unsigned int, f);
  unsigned int lsb = (bits >> 16) & 1u;
  return (bits + 0x7fffu + lsb) >> 16;
}

// Swizzled byte offset of element (row a, col k) inside a [128][256] bf16 tile.
// Row stride 512B; XOR bits 4-6 with (a&7) -> conflict-free ds_read_b128
// when 16 consecutive rows read the same 16B k-slice.
__device__ __forceinline__ int swz_off(int a, int k2bytes) {
  return ((a << 9) + k2bytes) ^ ((a & 7) << 4);
}

// Build per-agent: W1T fp32 [a][k] (coalesced matvec reads) and swizzled bf16 W1T tile.
__global__ __launch_bounds__(256) void prep_kernel(const float* __restrict__ W1,
                                                   unsigned short* __restrict__ Wt_g,
                                                   float* __restrict__ W1T) {
  int blk = blockIdx.x;          // 32 blocks = 4 agents x 8 chunks
  int i = blk >> 3;
  int chunk = blk & 7;
  const float* W1i = W1 + i * KKm * DDm;
  char* Wti = (char*)(Wt_g + i * 32768);
  float* W1Ti = W1T + i * DDm * KKm;
  int base = chunk * 4096;
  for (int idx = base + threadIdx.x; idx < base + 4096; idx += 256) {
    int a = idx >> 8;            // 0..127 (z-dim)
    int k = idx & 255;           // 0..255 (hidden)
    float v = W1i[k * DDm + a];
    W1Ti[a * KKm + k] = v;
    *(unsigned short*)(Wti + swz_off(a, k << 1)) = (unsigned short)f2bf(v);
  }
}

// One block = one (i,j) pair x 2 batches. 4 waves; wave handles 64x128 of one batch.
__global__ __launch_bounds__(256, 2) void hess_kernel(
    const float* __restrict__ z_all, const float* __restrict__ b1,
    const float* __restrict__ W2, const unsigned short* __restrict__ Wt_g,
    const float* __restrict__ W1T, float* __restrict__ out) {
  __shared__ __align__(16) unsigned short Wt[32768];   // 64KB swizzled bf16 W1_i^T
  __shared__ __align__(16) float s_lds[2][KKm];        // per-batch scale vectors

  int t = threadIdx.x;
  int blk = blockIdx.x;
  int pair = blk >> 7;            // 0..11
  int bgrp = blk & 127;           // batch pair index
  int i = pair / 3;
  int rr = pair - i * 3;
  int j = rr + (rr >= i ? 1 : 0);

  // --- issue async staging of W-tile (linear copy; layout pre-swizzled in global)
  {
    int wvi = t >> 6, lane = t & 63;
    const char* src = (const char*)(Wt_g + i * 32768);
#pragma unroll
    for (int it = 0; it < 16; ++it) {
      int off = (it * 4 + wvi) * 1024;
      __builtin_amdgcn_global_load_lds(
          (const __attribute__((address_space(1))) unsigned int*)(src + off + lane * 16),
          (__attribute__((address_space(3))) unsigned int*)((char*)Wt + off),
          16, 0, 0);
    }
  }

  // --- phase 1: s_k for both batches (fp32, coalesced over k=t) while DMA flies
  {
    const float* w = W1T + i * DDm * KKm + t;                 // W1T[i][a][t]
    const float* zj = z_all + ((size_t)j * BB + bgrp * 2) * DDm;
    float u0 = b1[i * KKm + t];
    float u1 = u0;
#pragma unroll 8
    for (int a = 0; a < DDm; ++a) {
      float wa = w[a * KKm];
      u0 = fmaf(wa, zj[a], u0);
      u1 = fmaf(wa, zj[DDm + a], u1);
    }
    float w2v = W2[i * KKm + t];
    float h0 = tanhf(u0), h1 = tanhf(u1);
    s_lds[0][t] = -2.0f * w2v * h0 * (1.0f - h0 * h0);
    s_lds[1][t] = -2.0f * w2v * h1 * (1.0f - h1 * h1);
  }
  __syncthreads();   // drains vmcnt too -> Wt ready

  int wvi = t >> 6, lane = t & 63;
  int bl = wvi >> 1;              // which batch of the 2
  int m0 = (wvi & 1) * 64;        // row half
  int g = lane >> 4;              // k-group 0..3
  int lr = lane & 15;             // row-in-tile / col-in-tile

  f32x4 acc[4][8];
#pragma unroll
  for (int mt = 0; mt < 4; ++mt)
#pragma unroll
    for (int nt = 0; nt < 8; ++nt) acc[mt][nt] = (f32x4){0.f, 0.f, 0.f, 0.f};

  for (int kc = 0; kc < 8; ++kc) {
    int kbyte = kc * 64 + g * 16;
    const f32x4* sp = (const f32x4*)&s_lds[bl][kc * 32 + g * 8];
    f32x4 sA = sp[0], sB = sp[1];
    float sv[8] = {sA[0], sA[1], sA[2], sA[3], sB[0], sB[1], sB[2], sB[3]};

    // A-fragments: s-scaled W rows (m side), built on the fly
    bf16x8 afr[4];
#pragma unroll
    for (int mt = 0; mt < 4; ++mt) {
      int row = m0 + mt * 16 + lr;
      u32x4 wq = *(const u32x4*)((const char*)Wt + swz_off(row, kbyte));
      u32x4 aq;
#pragma unroll
      for (int q = 0; q < 4; ++q) {
        float lo = __builtin_bit_cast(float, wq[q] << 16) * sv[2 * q];
        float hi = __builtin_bit_cast(float, wq[q] & 0xffff0000u) * sv[2 * q + 1];
        aq[q] = f2bf(lo) | (f2bf(hi) << 16);   // lo -> low half
      }
      afr[mt] = __builtin_bit_cast(bf16x8, aq);
    }

    // B-fragments: unscaled W rows (n side), stream through all 8 col-tiles
#pragma unroll
    for (int nt = 0; nt < 8; ++nt) {
      int row = nt * 16 + lr;
      bf16x8 bfr = __builtin_bit_cast(
          bf16x8, *(const u32x4*)((const char*)Wt + swz_off(row, kbyte)));
#pragma unroll
      for (int mt = 0; mt < 4; ++mt)
        acc[mt][nt] =
            __builtin_amdgcn_mfma_f32_16x16x32_bf16(afr[mt], bfr, acc[mt][nt], 0, 0, 0);
    }
  }

  // --- store: C element (row = tile_m + g*4 + q, col = tile_n + lr)
  int b = bgrp * 2 + bl;
  float* op = out + (((size_t)(i * NA + j) * BB + b) << 14);
#pragma unroll
  for (int mt = 0; mt < 4; ++mt) {
    int rbase = m0 + mt * 16 + g * 4;
#pragma unroll
    for (int nt = 0; nt < 8; ++nt) {
      int col = nt * 16 + lr;
#pragma unroll
      for (int q = 0; q < 4; ++q) op[(size_t)(rbase + q) * DDm + col] = acc[mt][nt][q];
    }
  }
}

extern "C" void kernel_launch(void* const* d_in, const int* in_sizes, int n_in,
                              void* d_out, int out_size, void* d_ws, size_t ws_size,
                              hipStream_t stream) {
  const float* z_all = (const float*)d_in[0];
  const float* W1 = (const float*)d_in[1];
  const float* b1 = (const float*)d_in[2];
  const float* W2 = (const float*)d_in[3];
  // b2 (d_in[4]) does not affect the Hessian
  float* out = (float*)d_out;

  unsigned short* Wt_g = (unsigned short*)d_ws;            // 256KB swizzled bf16
  float* W1T = (float*)((char*)d_ws + 262144);             // 512KB fp32 transpose

  // zero the 4 diagonal blocks (16MB each, contiguous)
  for (int i = 0; i < NA; ++i)
    (void)hipMemsetAsync((char*)d_out + (size_t)i * 5 * 16777216ull, 0, 16777216ull, stream);

  prep_kernel<<<32, 256, 0, stream>>>(W1, Wt_g, W1T);
  hess_kernel<<<12 * 128, 256, 0, stream>>>(z_all, b1, W2, Wt_g, W1T, out);
}

// Round 3
// 73.768 us; speedup vs baseline: 1.1943x; 1.1943x over previous
//
#include <hip/hip_runtime.h>
#include <hip/hip_bf16.h>

#define NA 4
#define BB 256
#define DDm 128
#define KKm 256   // hidden = 2*D

typedef __attribute__((ext_vector_type(4))) float f32x4;
typedef __attribute__((ext_vector_type(4))) unsigned int u32x4;
typedef __attribute__((ext_vector_type(8))) short bf16x8;

// RNE float -> bf16 bits
__device__ __forceinline__ unsigned int f2bf(float f) {
  unsigned int bits = __builtin_bit_cast(unsigned int, f);
  unsigned int lsb = (bits >> 16) & 1u;
  return (bits + 0x7fffu + lsb) >> 16;
}

// Swizzled byte offset of element (row a, col k) inside a [128][256] bf16 tile.
// Row stride 512B; XOR bits 4-6 with (a&7) -> conflict-free ds_read_b128
// when 16 consecutive rows read the same 16B k-slice.
__device__ __forceinline__ int swz_off(int a, int k2bytes) {
  return ((a << 9) + k2bytes) ^ ((a & 7) << 4);
}

// Build per-agent: W1T fp32 [a][k] (coalesced matvec reads) and swizzled bf16 W1T tile.
__global__ __launch_bounds__(256) void prep_kernel(const float* __restrict__ W1,
                                                   unsigned short* __restrict__ Wt_g,
                                                   float* __restrict__ W1T) {
  int blk = blockIdx.x;          // 32 blocks = 4 agents x 8 chunks
  int i = blk >> 3;
  int chunk = blk & 7;
  const float* W1i = W1 + i * KKm * DDm;
  char* Wti = (char*)(Wt_g + i * 32768);
  float* W1Ti = W1T + i * DDm * KKm;
  int base = chunk * 4096;
  for (int idx = base + threadIdx.x; idx < base + 4096; idx += 256) {
    int a = idx >> 8;            // 0..127 (z-dim)
    int k = idx & 255;           // 0..255 (hidden)
    float v = W1i[k * DDm + a];
    W1Ti[a * KKm + k] = v;
    *(unsigned short*)(Wti + swz_off(a, k << 1)) = (unsigned short)f2bf(v);
  }
}

// One block = one (i,j) pair x 2 batches. 4 waves; wave handles 64x128 of one batch.
// Diagonal pairs (i==j) just stream zeros (replaces hipMemsetAsync dispatches).
__global__ __launch_bounds__(256, 2) void hess_kernel(
    const float* __restrict__ z_all, const float* __restrict__ b1,
    const float* __restrict__ W2, const unsigned short* __restrict__ Wt_g,
    const float* __restrict__ W1T, float* __restrict__ out) {
  __shared__ __align__(16) unsigned short Wt[32768];   // 64KB swizzled bf16 W1_i^T
  __shared__ __align__(16) float s_lds[2][KKm];        // per-batch scale vectors

  int t = threadIdx.x;
  int blk = blockIdx.x;
  int pair = blk >> 7;            // 0..15 (all i,j including diagonal)
  int bgrp = blk & 127;           // batch pair index
  int i = pair >> 2;
  int j = pair & 3;

  if (i == j) {
    // zero 2 batches' worth of this diagonal block: 32768 floats
    f32x4* zp = (f32x4*)(out + (((size_t)pair * BB + bgrp * 2) << 14));
    f32x4 z4 = (f32x4){0.f, 0.f, 0.f, 0.f};
#pragma unroll
    for (int q = 0; q < 32; ++q) zp[q * 256 + t] = z4;
    return;
  }

  // --- issue async staging of W-tile (linear copy; layout pre-swizzled in global)
  {
    int wvi = t >> 6, lane = t & 63;
    const char* src = (const char*)(Wt_g + i * 32768);
#pragma unroll
    for (int it = 0; it < 16; ++it) {
      int off = (it * 4 + wvi) * 1024;
      __builtin_amdgcn_global_load_lds(
          (const __attribute__((address_space(1))) unsigned int*)(src + off + lane * 16),
          (__attribute__((address_space(3))) unsigned int*)((char*)Wt + off),
          16, 0, 0);
    }
  }

  // --- phase 1: s_k for both batches (fp32, coalesced over k=t) while DMA flies
  {
    const float* w = W1T + i * DDm * KKm + t;                 // W1T[i][a][t]
    const float* zj = z_all + ((size_t)j * BB + bgrp * 2) * DDm;
    float u0 = b1[i * KKm + t];
    float u1 = u0;
#pragma unroll 8
    for (int a = 0; a < DDm; ++a) {
      float wa = w[a * KKm];
      u0 = fmaf(wa, zj[a], u0);
      u1 = fmaf(wa, zj[DDm + a], u1);
    }
    float w2v = W2[i * KKm + t];
    float h0 = tanhf(u0), h1 = tanhf(u1);
    s_lds[0][t] = -2.0f * w2v * h0 * (1.0f - h0 * h0);
    s_lds[1][t] = -2.0f * w2v * h1 * (1.0f - h1 * h1);
  }
  __syncthreads();   // drains vmcnt too -> Wt ready

  int wvi = t >> 6, lane = t & 63;
  int bl = wvi >> 1;              // which batch of the 2
  int m0 = (wvi & 1) * 64;        // row half
  int g = lane >> 4;              // k-group 0..3
  int lr = lane & 15;             // row-in-tile / col-in-tile

  f32x4 acc[4][8];
#pragma unroll
  for (int mt = 0; mt < 4; ++mt)
#pragma unroll
    for (int nt = 0; nt < 8; ++nt) acc[mt][nt] = (f32x4){0.f, 0.f, 0.f, 0.f};

  for (int kc = 0; kc < 8; ++kc) {
    int kbyte = kc * 64 + g * 16;
    const f32x4* sp = (const f32x4*)&s_lds[bl][kc * 32 + g * 8];
    f32x4 sA = sp[0], sB = sp[1];
    float sv[8] = {sA[0], sA[1], sA[2], sA[3], sB[0], sB[1], sB[2], sB[3]};

    // A-fragments: s-scaled W rows (m side), built on the fly
    bf16x8 afr[4];
#pragma unroll
    for (int mt = 0; mt < 4; ++mt) {
      int row = m0 + mt * 16 + lr;
      u32x4 wq = *(const u32x4*)((const char*)Wt + swz_off(row, kbyte));
      u32x4 aq;
#pragma unroll
      for (int q = 0; q < 4; ++q) {
        float lo = __builtin_bit_cast(float, wq[q] << 16) * sv[2 * q];
        float hi = __builtin_bit_cast(float, wq[q] & 0xffff0000u) * sv[2 * q + 1];
        aq[q] = f2bf(lo) | (f2bf(hi) << 16);   // lo -> low half
      }
      afr[mt] = __builtin_bit_cast(bf16x8, aq);
    }

    // B-fragments: unscaled W rows (n side), stream through all 8 col-tiles
#pragma unroll
    for (int nt = 0; nt < 8; ++nt) {
      int row = nt * 16 + lr;
      bf16x8 bfr = __builtin_bit_cast(
          bf16x8, *(const u32x4*)((const char*)Wt + swz_off(row, kbyte)));
#pragma unroll
      for (int mt = 0; mt < 4; ++mt)
        acc[mt][nt] =
            __builtin_amdgcn_mfma_f32_16x16x32_bf16(afr[mt], bfr, acc[mt][nt], 0, 0, 0);
    }
  }

  // --- store: C element (row = tile_m + g*4 + q, col = tile_n + lr)
  int b = bgrp * 2 + bl;
  float* op = out + (((size_t)pair * BB + b) << 14);
#pragma unroll
  for (int mt = 0; mt < 4; ++mt) {
    int rbase = m0 + mt * 16 + g * 4;
#pragma unroll
    for (int nt = 0; nt < 8; ++nt) {
      int col = nt * 16 + lr;
#pragma unroll
      for (int q = 0; q < 4; ++q) op[(size_t)(rbase + q) * DDm + col] = acc[mt][nt][q];
    }
  }
}

extern "C" void kernel_launch(void* const* d_in, const int* in_sizes, int n_in,
                              void* d_out, int out_size, void* d_ws, size_t ws_size,
                              hipStream_t stream) {
  const float* z_all = (const float*)d_in[0];
  const float* W1 = (const float*)d_in[1];
  const float* b1 = (const float*)d_in[2];
  const float* W2 = (const float*)d_in[3];
  // b2 (d_in[4]) does not affect the Hessian
  float* out = (float*)d_out;

  unsigned short* Wt_g = (unsigned short*)d_ws;            // 256KB swizzled bf16
  float* W1T = (float*)((char*)d_ws + 262144);             // 512KB fp32 transpose

  prep_kernel<<<32, 256, 0, stream>>>(W1, Wt_g, W1T);
  hess_kernel<<<16 * 128, 256, 0, stream>>>(z_all, b1, W2, Wt_g, W1T, out);
}